// Round 1
// baseline (344.111 us; speedup 1.0000x reference)
//
#include <hip/hip_runtime.h>

#define BLOCK 256

// ---------------------------------------------------------------------------
// Kernel 1: per-face precompute.
// Builds SoA float4 tables in workspace:
//   cent[f] = centroid (xyz)
//   v1/v2/v3[f] = the three gathered vertices (xyz)
//   jd0[f] = (e0.xyz, dot(w1,e0))
//   jd1[f] = (e1.xyz, dot(w1,e1))
//   jd2[f] = (d11/denom, d01/denom, d00/denom, 0)   [denom = d00*d11 - d01^2]
// ---------------------------------------------------------------------------
__global__ void face_pre_kernel(const float* __restrict__ verts,
                                const int* __restrict__ faces,
                                int F,
                                float4* __restrict__ cent,
                                float4* __restrict__ v1,
                                float4* __restrict__ v2,
                                float4* __restrict__ v3,
                                float4* __restrict__ jd0,
                                float4* __restrict__ jd1,
                                float4* __restrict__ jd2) {
    int f = blockIdx.x * blockDim.x + threadIdx.x;
    if (f >= F) return;
    int i0 = faces[3 * f + 0];
    int i1 = faces[3 * f + 1];
    int i2 = faces[3 * f + 2];
    float ax = verts[3 * i0 + 0], ay = verts[3 * i0 + 1], az = verts[3 * i0 + 2];
    float bx = verts[3 * i1 + 0], by = verts[3 * i1 + 1], bz = verts[3 * i1 + 2];
    float cx = verts[3 * i2 + 0], cy = verts[3 * i2 + 1], cz = verts[3 * i2 + 2];

    float e0x = bx - ax, e0y = by - ay, e0z = bz - az;
    float e1x = cx - ax, e1y = cy - ay, e1z = cz - az;

    float d00 = e0x * e0x + e0y * e0y + e0z * e0z;
    float d01 = e0x * e1x + e0y * e1y + e0z * e1z;
    float d11 = e1x * e1x + e1y * e1y + e1z * e1z;
    float inv = 1.0f / (d00 * d11 - d01 * d01);

    float w1e0 = ax * e0x + ay * e0y + az * e0z;
    float w1e1 = ax * e1x + ay * e1y + az * e1z;

    const float third = 1.0f / 3.0f;
    cent[f] = make_float4((ax + bx + cx) * third,
                          (ay + by + cy) * third,
                          (az + bz + cz) * third, 0.0f);
    v1[f] = make_float4(ax, ay, az, 0.0f);
    v2[f] = make_float4(bx, by, bz, 0.0f);
    v3[f] = make_float4(cx, cy, cz, 0.0f);
    jd0[f] = make_float4(e0x, e0y, e0z, w1e0);
    jd1[f] = make_float4(e1x, e1y, e1z, w1e1);
    jd2[f] = make_float4(d11 * inv, d01 * inv, d00 * inv, 0.0f);
}

// ---------------------------------------------------------------------------
// Kernel 2: pair kernel. 2D grid: blockIdx.y = i (uniform per block),
// blockIdx.x*256+tid = j. Each thread decides hit(i,j); ballot+popcount per
// wave; one float atomicAdd of face_probs[i]*count per block.
//
// Barycentric per sample s:
//   d20 = dot(sampled[i,s], e0_j) - dot(w1_j, e0_j)
//       = al*p0 + be*p1 + ga*p2 - w1e0   (dots distributed over the blend)
//   v = A*d20 - B*d21 ; w = C*d21 - B*d20 ; u = 1 - v - w
// ---------------------------------------------------------------------------
__global__ void __launch_bounds__(BLOCK)
pair_kernel(const float4* __restrict__ cent,
            const float4* __restrict__ v1,
            const float4* __restrict__ v2,
            const float4* __restrict__ v3,
            const float4* __restrict__ jd0,
            const float4* __restrict__ jd1,
            const float4* __restrict__ jd2,
            const float* __restrict__ alpha,
            const float* __restrict__ beta,
            const float* __restrict__ face_probs,
            int F, int S,
            float* __restrict__ acc) {
    const int i = blockIdx.y;                       // wave-uniform
    const int j = blockIdx.x * BLOCK + threadIdx.x;

    bool counted = false;
    if (j < F && j != i) {
        float4 cj = cent[j];          // coalesced over j
        float4 ci = cent[i];          // uniform -> scalar load
        float dx = ci.x - cj.x, dy = ci.y - cj.y, dz = ci.z - cj.z;
        float d2 = dx * dx + dy * dy + dz * dz;
        if (d2 < 1.0f) {
            float4 b0 = jd0[j];
            float4 b1 = jd1[j];
            float4 b2 = jd2[j];
            float4 a1 = v1[i];
            float4 a2 = v2[i];
            float4 a3 = v3[i];
            // 6 dot products: i's three vertices vs j's two edges
            float p0 = a1.x * b0.x + a1.y * b0.y + a1.z * b0.z;
            float p1 = a2.x * b0.x + a2.y * b0.y + a2.z * b0.z;
            float p2 = a3.x * b0.x + a3.y * b0.y + a3.z * b0.z;
            float q0 = a1.x * b1.x + a1.y * b1.y + a1.z * b1.z;
            float q1 = a2.x * b1.x + a2.y * b1.y + a2.z * b1.z;
            float q2 = a3.x * b1.x + a3.y * b1.y + a3.z * b1.z;
            float w1e0 = b0.w, w1e1 = b1.w;
            float A = b2.x, B = b2.y, C = b2.z;

            const float* al_row = alpha + (long long)i * S;   // uniform rows
            const float* be_row = beta + (long long)i * S;
            for (int s = 0; s < S; ++s) {
                float al = al_row[s];
                float be = be_row[s];
                float ga = 1.0f - al - be;
                float d20 = al * p0 + be * p1 + ga * p2 - w1e0;
                float d21 = al * q0 + be * q1 + ga * q2 - w1e1;
                float vv = A * d20 - B * d21;
                float ww = C * d21 - B * d20;
                float uu = 1.0f - vv - ww;
                if (uu >= 0.0f && vv >= 0.0f && ww >= 0.0f) {
                    counted = true;
                    break;
                }
            }
        }
    }

    unsigned long long m = __ballot(counted);
    __shared__ int wave_cnt[BLOCK / 64];
    if ((threadIdx.x & 63) == 0) wave_cnt[threadIdx.x >> 6] = __popcll(m);
    __syncthreads();
    if (threadIdx.x == 0) {
        int tot = 0;
#pragma unroll
        for (int w = 0; w < BLOCK / 64; ++w) tot += wave_cnt[w];
        if (tot > 0) atomicAdd(acc, face_probs[i] * (float)tot);
    }
}

// ---------------------------------------------------------------------------
// Kernel 3: finalize — out = acc / F
// ---------------------------------------------------------------------------
__global__ void finalize_kernel(const float* __restrict__ acc,
                                float* __restrict__ out, float invF) {
    if (threadIdx.x == 0 && blockIdx.x == 0) out[0] = acc[0] * invF;
}

extern "C" void kernel_launch(void* const* d_in, const int* in_sizes, int n_in,
                              void* d_out, int out_size, void* d_ws, size_t ws_size,
                              hipStream_t stream) {
    const float* vertices   = (const float*)d_in[0];
    const int*   faces      = (const int*)d_in[1];
    const float* face_probs = (const float*)d_in[2];
    const float* alpha      = (const float*)d_in[3];
    const float* beta       = (const float*)d_in[4];
    float* out = (float*)d_out;

    const int F = in_sizes[2];
    const int S = in_sizes[3] / F;

    // Workspace layout (16B-aligned): acc scalar, then 7 float4 tables of F.
    char* ws = (char*)d_ws;
    float*  acc  = (float*)ws;
    float4* cent = (float4*)(ws + 16);
    float4* v1   = cent + F;
    float4* v2   = v1 + F;
    float4* v3   = v2 + F;
    float4* jd0  = v3 + F;
    float4* jd1  = jd0 + F;
    float4* jd2  = jd1 + F;

    hipMemsetAsync(acc, 0, sizeof(float), stream);

    face_pre_kernel<<<(F + BLOCK - 1) / BLOCK, BLOCK, 0, stream>>>(
        vertices, faces, F, cent, v1, v2, v3, jd0, jd1, jd2);

    dim3 grid((F + BLOCK - 1) / BLOCK, F);
    pair_kernel<<<grid, BLOCK, 0, stream>>>(
        cent, v1, v2, v3, jd0, jd1, jd2, alpha, beta, face_probs, F, S, acc);

    finalize_kernel<<<1, 64, 0, stream>>>(acc, out, 1.0f / (float)F);
}

// Round 2
// 99.322 us; speedup vs baseline: 3.4646x; 3.4646x over previous
//
#include <hip/hip_runtime.h>

#define BLOCK 256
#define MAX_S 32

// ---------------------------------------------------------------------------
// Kernel 1: per-face precompute (unchanged from R1).
//   cent[f] = centroid (xyz)
//   v1/v2/v3[f] = gathered vertices
//   jd0[f] = (e0.xyz, dot(w1,e0))
//   jd1[f] = (e1.xyz, dot(w1,e1))
//   jd2[f] = (d11/denom, d01/denom, d00/denom, 0)
// ---------------------------------------------------------------------------
__global__ void face_pre_kernel(const float* __restrict__ verts,
                                const int* __restrict__ faces,
                                int F,
                                float4* __restrict__ cent,
                                float4* __restrict__ v1,
                                float4* __restrict__ v2,
                                float4* __restrict__ v3,
                                float4* __restrict__ jd0,
                                float4* __restrict__ jd1,
                                float4* __restrict__ jd2) {
    int f = blockIdx.x * blockDim.x + threadIdx.x;
    if (f >= F) return;
    int i0 = faces[3 * f + 0];
    int i1 = faces[3 * f + 1];
    int i2 = faces[3 * f + 2];
    float ax = verts[3 * i0 + 0], ay = verts[3 * i0 + 1], az = verts[3 * i0 + 2];
    float bx = verts[3 * i1 + 0], by = verts[3 * i1 + 1], bz = verts[3 * i1 + 2];
    float cx = verts[3 * i2 + 0], cy = verts[3 * i2 + 1], cz = verts[3 * i2 + 2];

    float e0x = bx - ax, e0y = by - ay, e0z = bz - az;
    float e1x = cx - ax, e1y = cy - ay, e1z = cz - az;

    float d00 = e0x * e0x + e0y * e0y + e0z * e0z;
    float d01 = e0x * e1x + e0y * e1y + e0z * e1z;
    float d11 = e1x * e1x + e1y * e1y + e1z * e1z;
    float inv = 1.0f / (d00 * d11 - d01 * d01);

    float w1e0 = ax * e0x + ay * e0y + az * e0z;
    float w1e1 = ax * e1x + ay * e1y + az * e1z;

    const float third = 1.0f / 3.0f;
    cent[f] = make_float4((ax + bx + cx) * third,
                          (ay + by + cy) * third,
                          (az + bz + cz) * third, 0.0f);
    v1[f] = make_float4(ax, ay, az, 0.0f);
    v2[f] = make_float4(bx, by, bz, 0.0f);
    v3[f] = make_float4(cx, cy, cz, 0.0f);
    jd0[f] = make_float4(e0x, e0y, e0z, w1e0);
    jd1[f] = make_float4(e1x, e1y, e1z, w1e1);
    jd2[f] = make_float4(d11 * inv, d01 * inv, d00 * inv, 0.0f);
}

// ---------------------------------------------------------------------------
// Kernel 2: pair kernel, one block per i. Threads grid-stride over j
// (F/BLOCK iterations). i-side data in registers (loaded once), alpha/beta
// row staged in LDS. Per-thread hit count -> shuffle reduce -> ONE plain
// store per block (partial[i]); NO contended atomics.
// ---------------------------------------------------------------------------
__global__ void __launch_bounds__(BLOCK)
pair_kernel(const float4* __restrict__ cent,
            const float4* __restrict__ v1,
            const float4* __restrict__ v2,
            const float4* __restrict__ v3,
            const float4* __restrict__ jd0,
            const float4* __restrict__ jd1,
            const float4* __restrict__ jd2,
            const float* __restrict__ alpha,
            const float* __restrict__ beta,
            const float* __restrict__ face_probs,
            int F, int S,
            float* __restrict__ partial) {
    const int i = blockIdx.x;
    const int tid = threadIdx.x;

    __shared__ float s_al[MAX_S];
    __shared__ float s_be[MAX_S];
    if (tid < S) {
        s_al[tid] = alpha[(long long)i * S + tid];
        s_be[tid] = beta[(long long)i * S + tid];
    }
    __syncthreads();

    // i-side data: uniform, loaded once, held in registers for all j iters
    const float4 ci = cent[i];
    const float4 a1 = v1[i];
    const float4 a2 = v2[i];
    const float4 a3 = v3[i];

    int count = 0;
    for (int j = tid; j < F; j += BLOCK) {
        if (j == i) continue;
        float4 cj = cent[j];                     // coalesced over j
        float dx = ci.x - cj.x, dy = ci.y - cj.y, dz = ci.z - cj.z;
        float d2 = dx * dx + dy * dy + dz * dz;
        if (d2 >= 1.0f) continue;

        float4 b0 = jd0[j];
        float4 b1 = jd1[j];
        float4 b2 = jd2[j];
        // 6 dot products: i's three vertices vs j's two edges
        float p0 = a1.x * b0.x + a1.y * b0.y + a1.z * b0.z;
        float p1 = a2.x * b0.x + a2.y * b0.y + a2.z * b0.z;
        float p2 = a3.x * b0.x + a3.y * b0.y + a3.z * b0.z;
        float q0 = a1.x * b1.x + a1.y * b1.y + a1.z * b1.z;
        float q1 = a2.x * b1.x + a2.y * b1.y + a2.z * b1.z;
        float q2 = a3.x * b1.x + a3.y * b1.y + a3.z * b1.z;
        float w1e0 = b0.w, w1e1 = b1.w;
        float A = b2.x, B = b2.y, C = b2.z;

        for (int s = 0; s < S; ++s) {
            float al = s_al[s];
            float be = s_be[s];
            float ga = 1.0f - al - be;
            float d20 = al * p0 + be * p1 + ga * p2 - w1e0;
            float d21 = al * q0 + be * q1 + ga * q2 - w1e1;
            float vv = A * d20 - B * d21;
            float ww = C * d21 - B * d20;
            float uu = 1.0f - vv - ww;
            if (uu >= 0.0f && vv >= 0.0f && ww >= 0.0f) {
                ++count;
                break;
            }
        }
    }

    // wave reduce (64 lanes), then cross-wave via LDS
    for (int off = 32; off > 0; off >>= 1)
        count += __shfl_down(count, off, 64);
    __shared__ int wave_cnt[BLOCK / 64];
    if ((tid & 63) == 0) wave_cnt[tid >> 6] = count;
    __syncthreads();
    if (tid == 0) {
        int tot = 0;
#pragma unroll
        for (int w = 0; w < BLOCK / 64; ++w) tot += wave_cnt[w];
        partial[i] = face_probs[i] * (float)tot;   // unique slot, no atomic
    }
}

// ---------------------------------------------------------------------------
// Kernel 3: reduce partial[0..F) -> out[0] = sum / F. Single block.
// ---------------------------------------------------------------------------
__global__ void __launch_bounds__(BLOCK)
reduce_kernel(const float* __restrict__ partial, float* __restrict__ out,
              int F, float invF) {
    const int tid = threadIdx.x;
    float sum = 0.0f;
    for (int f = tid; f < F; f += BLOCK) sum += partial[f];
    for (int off = 32; off > 0; off >>= 1)
        sum += __shfl_down(sum, off, 64);
    __shared__ float wave_sum[BLOCK / 64];
    if ((tid & 63) == 0) wave_sum[tid >> 6] = sum;
    __syncthreads();
    if (tid == 0) {
        float tot = 0.0f;
#pragma unroll
        for (int w = 0; w < BLOCK / 64; ++w) tot += wave_sum[w];
        out[0] = tot * invF;
    }
}

extern "C" void kernel_launch(void* const* d_in, const int* in_sizes, int n_in,
                              void* d_out, int out_size, void* d_ws, size_t ws_size,
                              hipStream_t stream) {
    const float* vertices   = (const float*)d_in[0];
    const int*   faces      = (const int*)d_in[1];
    const float* face_probs = (const float*)d_in[2];
    const float* alpha      = (const float*)d_in[3];
    const float* beta       = (const float*)d_in[4];
    float* out = (float*)d_out;

    const int F = in_sizes[2];
    const int S = in_sizes[3] / F;

    // Workspace layout (16B-aligned): 7 float4 tables of F, then F partials.
    char* ws = (char*)d_ws;
    float4* cent = (float4*)ws;
    float4* v1   = cent + F;
    float4* v2   = v1 + F;
    float4* v3   = v2 + F;
    float4* jd0  = v3 + F;
    float4* jd1  = jd0 + F;
    float4* jd2  = jd1 + F;
    float* partial = (float*)(jd2 + F);

    face_pre_kernel<<<(F + BLOCK - 1) / BLOCK, BLOCK, 0, stream>>>(
        vertices, faces, F, cent, v1, v2, v3, jd0, jd1, jd2);

    pair_kernel<<<F, BLOCK, 0, stream>>>(
        cent, v1, v2, v3, jd0, jd1, jd2, alpha, beta, face_probs, F, S, partial);

    reduce_kernel<<<1, BLOCK, 0, stream>>>(partial, out, F, 1.0f / (float)F);
}

// Round 3
// 82.113 us; speedup vs baseline: 4.1907x; 1.2096x over previous
//
#include <hip/hip_runtime.h>

#define BLOCK 256

// ---------------------------------------------------------------------------
// Kernel 1: per-face precompute.
//   cent[f] = centroid (xyz)
//   v1/v2/v3[f] = gathered vertices
//   jd0[f] = (e0.xyz, dot(w1,e0))
//   jd1[f] = (e1.xyz, dot(w1,e1))
//   jd2[f] = (d11/denom, d01/denom, d00/denom, 0)
// ---------------------------------------------------------------------------
__global__ void face_pre_kernel(const float* __restrict__ verts,
                                const int* __restrict__ faces,
                                int F,
                                float4* __restrict__ cent,
                                float4* __restrict__ v1,
                                float4* __restrict__ v2,
                                float4* __restrict__ v3,
                                float4* __restrict__ jd0,
                                float4* __restrict__ jd1,
                                float4* __restrict__ jd2) {
    int f = blockIdx.x * blockDim.x + threadIdx.x;
    if (f >= F) return;
    int i0 = faces[3 * f + 0];
    int i1 = faces[3 * f + 1];
    int i2 = faces[3 * f + 2];
    float ax = verts[3 * i0 + 0], ay = verts[3 * i0 + 1], az = verts[3 * i0 + 2];
    float bx = verts[3 * i1 + 0], by = verts[3 * i1 + 1], bz = verts[3 * i1 + 2];
    float cx = verts[3 * i2 + 0], cy = verts[3 * i2 + 1], cz = verts[3 * i2 + 2];

    float e0x = bx - ax, e0y = by - ay, e0z = bz - az;
    float e1x = cx - ax, e1y = cy - ay, e1z = cz - az;

    float d00 = e0x * e0x + e0y * e0y + e0z * e0z;
    float d01 = e0x * e1x + e0y * e1y + e0z * e1z;
    float d11 = e1x * e1x + e1y * e1y + e1z * e1z;
    float inv = 1.0f / (d00 * d11 - d01 * d01);

    float w1e0 = ax * e0x + ay * e0y + az * e0z;
    float w1e1 = ax * e1x + ay * e1y + az * e1z;

    const float third = 1.0f / 3.0f;
    cent[f] = make_float4((ax + bx + cx) * third,
                          (ay + by + cy) * third,
                          (az + bz + cz) * third, 0.0f);
    v1[f] = make_float4(ax, ay, az, 0.0f);
    v2[f] = make_float4(bx, by, bz, 0.0f);
    v3[f] = make_float4(cx, cy, cz, 0.0f);
    jd0[f] = make_float4(e0x, e0y, e0z, w1e0);
    jd1[f] = make_float4(e1x, e1y, e1z, w1e1);
    jd2[f] = make_float4(d11 * inv, d01 * inv, d00 * inv, 0.0f);
}

__device__ __forceinline__ float sgpr_broadcast(float v) {
    union { float f; int i; } u;
    u.f = v;
    u.i = __builtin_amdgcn_readfirstlane(u.i);
    return u.f;
}

// ---------------------------------------------------------------------------
// Kernel 2: pair kernel, one block per i, 8 j per thread, branchless inner.
//
// Key identity: v, w, u are each AFFINE in (alpha, beta):
//   d20(s) = base0 + al*P0 + be*P1   (base0 = p2 - w1e0, P0 = p0-p2, P1 = p1-p2)
//   v = A*d20 - B*d21  =>  v = VB + al*V0 + be*V1   (fold once per pair)
// Per sample: 3x 2-FMA chains + min3 + max  (7 instr, no branches, no LDS).
// alpha/beta rows are block-uniform -> forced to SGPRs via readfirstlane.
// ---------------------------------------------------------------------------
template <int SS>
__global__ void __launch_bounds__(BLOCK)
pair_kernel(const float4* __restrict__ cent,
            const float4* __restrict__ v1,
            const float4* __restrict__ v2,
            const float4* __restrict__ v3,
            const float4* __restrict__ jd0,
            const float4* __restrict__ jd1,
            const float4* __restrict__ jd2,
            const float* __restrict__ alpha,
            const float* __restrict__ beta,
            const float* __restrict__ face_probs,
            int F,
            float* __restrict__ partial) {
    const int i = blockIdx.x;
    const int tid = threadIdx.x;

    // alpha/beta rows -> SGPRs (block-uniform)
    float al[SS], be[SS];
#pragma unroll
    for (int s = 0; s < SS; ++s) {
        al[s] = sgpr_broadcast(alpha[i * SS + s]);
        be[s] = sgpr_broadcast(beta[i * SS + s]);
    }

    // i-side data: uniform, in registers for all j iters
    const float4 ci = cent[i];
    const float4 a1 = v1[i];
    const float4 a2 = v2[i];
    const float4 a3 = v3[i];

    int count = 0;
    for (int j = tid; j < F; j += BLOCK) {
        float4 cj = cent[j];                     // coalesced over j
        float dx = ci.x - cj.x, dy = ci.y - cj.y, dz = ci.z - cj.z;
        float d2 = dx * dx + dy * dy + dz * dz;
        bool near = (d2 < 1.0f) && (j != i);
        if (!near) continue;                     // lane-masks the loads below

        float4 b0 = jd0[j];
        float4 b1 = jd1[j];
        float4 b2 = jd2[j];
        // 6 dots: i's three vertices vs j's two edges
        float p0 = a1.x * b0.x + a1.y * b0.y + a1.z * b0.z;
        float p1 = a2.x * b0.x + a2.y * b0.y + a2.z * b0.z;
        float p2 = a3.x * b0.x + a3.y * b0.y + a3.z * b0.z;
        float q0 = a1.x * b1.x + a1.y * b1.y + a1.z * b1.z;
        float q1 = a2.x * b1.x + a2.y * b1.y + a2.z * b1.z;
        float q2 = a3.x * b1.x + a3.y * b1.y + a3.z * b1.z;
        float A = b2.x, B = b2.y, C = b2.z;

        float base0 = p2 - b0.w, P0 = p0 - p2, P1 = p1 - p2;
        float base1 = q2 - b1.w, Q0 = q0 - q2, Q1 = q1 - q2;

        // fold: v = VB + al*V0 + be*V1 ; w = WB + al*W0 + be*W1 ; u = 1-v-w
        float VB = A * base0 - B * base1;
        float V0 = A * P0 - B * Q0;
        float V1 = A * P1 - B * Q1;
        float WB = C * base1 - B * base0;
        float W0 = C * Q0 - B * P0;
        float W1 = C * Q1 - B * P1;
        float UB = 1.0f - VB - WB;
        float U0 = -V0 - W0;
        float U1 = -V1 - W1;

        float best = -1.0f;
#pragma unroll
        for (int s = 0; s < SS; ++s) {
            float vv = fmaf(be[s], V1, fmaf(al[s], V0, VB));
            float ww = fmaf(be[s], W1, fmaf(al[s], W0, WB));
            float uu = fmaf(be[s], U1, fmaf(al[s], U0, UB));
            float m = fminf(uu, fminf(vv, ww));  // v_min3
            best = fmaxf(best, m);
        }
        count += (best >= 0.0f) ? 1 : 0;
    }

    // wave reduce (64 lanes), then cross-wave via LDS
    for (int off = 32; off > 0; off >>= 1)
        count += __shfl_down(count, off, 64);
    __shared__ int wave_cnt[BLOCK / 64];
    if ((tid & 63) == 0) wave_cnt[tid >> 6] = count;
    __syncthreads();
    if (tid == 0) {
        int tot = 0;
#pragma unroll
        for (int w = 0; w < BLOCK / 64; ++w) tot += wave_cnt[w];
        partial[i] = face_probs[i] * (float)tot;   // unique slot, no atomic
    }
}

// Generic-S fallback (LDS staging, dynamic loop) — only used if S != 10.
__global__ void __launch_bounds__(BLOCK)
pair_kernel_generic(const float4* __restrict__ cent,
                    const float4* __restrict__ v1,
                    const float4* __restrict__ v2,
                    const float4* __restrict__ v3,
                    const float4* __restrict__ jd0,
                    const float4* __restrict__ jd1,
                    const float4* __restrict__ jd2,
                    const float* __restrict__ alpha,
                    const float* __restrict__ beta,
                    const float* __restrict__ face_probs,
                    int F, int S,
                    float* __restrict__ partial) {
    const int i = blockIdx.x;
    const int tid = threadIdx.x;
    extern __shared__ float smem[];
    float* s_al = smem;
    float* s_be = smem + S;
    for (int s = tid; s < S; s += BLOCK) {
        s_al[s] = alpha[(long long)i * S + s];
        s_be[s] = beta[(long long)i * S + s];
    }
    __syncthreads();

    const float4 ci = cent[i];
    const float4 a1 = v1[i];
    const float4 a2 = v2[i];
    const float4 a3 = v3[i];

    int count = 0;
    for (int j = tid; j < F; j += BLOCK) {
        float4 cj = cent[j];
        float dx = ci.x - cj.x, dy = ci.y - cj.y, dz = ci.z - cj.z;
        float d2 = dx * dx + dy * dy + dz * dz;
        bool near = (d2 < 1.0f) && (j != i);
        if (!near) continue;

        float4 b0 = jd0[j];
        float4 b1 = jd1[j];
        float4 b2 = jd2[j];
        float p0 = a1.x * b0.x + a1.y * b0.y + a1.z * b0.z;
        float p1 = a2.x * b0.x + a2.y * b0.y + a2.z * b0.z;
        float p2 = a3.x * b0.x + a3.y * b0.y + a3.z * b0.z;
        float q0 = a1.x * b1.x + a1.y * b1.y + a1.z * b1.z;
        float q1 = a2.x * b1.x + a2.y * b1.y + a2.z * b1.z;
        float q2 = a3.x * b1.x + a3.y * b1.y + a3.z * b1.z;
        float A = b2.x, B = b2.y, C = b2.z;
        float base0 = p2 - b0.w, P0 = p0 - p2, P1 = p1 - p2;
        float base1 = q2 - b1.w, Q0 = q0 - q2, Q1 = q1 - q2;
        float VB = A * base0 - B * base1;
        float V0 = A * P0 - B * Q0;
        float V1 = A * P1 - B * Q1;
        float WB = C * base1 - B * base0;
        float W0 = C * Q0 - B * P0;
        float W1 = C * Q1 - B * P1;
        float UB = 1.0f - VB - WB;
        float U0 = -V0 - W0;
        float U1 = -V1 - W1;
        float best = -1.0f;
        for (int s = 0; s < S; ++s) {
            float alv = s_al[s], bev = s_be[s];
            float vv = fmaf(bev, V1, fmaf(alv, V0, VB));
            float ww = fmaf(bev, W1, fmaf(alv, W0, WB));
            float uu = fmaf(bev, U1, fmaf(alv, U0, UB));
            best = fmaxf(best, fminf(uu, fminf(vv, ww)));
        }
        count += (best >= 0.0f) ? 1 : 0;
    }

    for (int off = 32; off > 0; off >>= 1)
        count += __shfl_down(count, off, 64);
    __shared__ int wave_cnt[BLOCK / 64];
    if ((tid & 63) == 0) wave_cnt[tid >> 6] = count;
    __syncthreads();
    if (tid == 0) {
        int tot = 0;
#pragma unroll
        for (int w = 0; w < BLOCK / 64; ++w) tot += wave_cnt[w];
        partial[i] = face_probs[i] * (float)tot;
    }
}

// ---------------------------------------------------------------------------
// Kernel 3: reduce partial[0..F) -> out[0] = sum / F. Single block.
// ---------------------------------------------------------------------------
__global__ void __launch_bounds__(BLOCK)
reduce_kernel(const float* __restrict__ partial, float* __restrict__ out,
              int F, float invF) {
    const int tid = threadIdx.x;
    float sum = 0.0f;
    for (int f = tid; f < F; f += BLOCK) sum += partial[f];
    for (int off = 32; off > 0; off >>= 1)
        sum += __shfl_down(sum, off, 64);
    __shared__ float wave_sum[BLOCK / 64];
    if ((tid & 63) == 0) wave_sum[tid >> 6] = sum;
    __syncthreads();
    if (tid == 0) {
        float tot = 0.0f;
#pragma unroll
        for (int w = 0; w < BLOCK / 64; ++w) tot += wave_sum[w];
        out[0] = tot * invF;
    }
}

extern "C" void kernel_launch(void* const* d_in, const int* in_sizes, int n_in,
                              void* d_out, int out_size, void* d_ws, size_t ws_size,
                              hipStream_t stream) {
    const float* vertices   = (const float*)d_in[0];
    const int*   faces      = (const int*)d_in[1];
    const float* face_probs = (const float*)d_in[2];
    const float* alpha      = (const float*)d_in[3];
    const float* beta       = (const float*)d_in[4];
    float* out = (float*)d_out;

    const int F = in_sizes[2];
    const int S = in_sizes[3] / F;

    // Workspace layout (16B-aligned): 7 float4 tables of F, then F partials.
    char* ws = (char*)d_ws;
    float4* cent = (float4*)ws;
    float4* v1   = cent + F;
    float4* v2   = v1 + F;
    float4* v3   = v2 + F;
    float4* jd0  = v3 + F;
    float4* jd1  = jd0 + F;
    float4* jd2  = jd1 + F;
    float* partial = (float*)(jd2 + F);

    face_pre_kernel<<<(F + BLOCK - 1) / BLOCK, BLOCK, 0, stream>>>(
        vertices, faces, F, cent, v1, v2, v3, jd0, jd1, jd2);

    if (S == 10) {
        pair_kernel<10><<<F, BLOCK, 0, stream>>>(
            cent, v1, v2, v3, jd0, jd1, jd2, alpha, beta, face_probs, F, partial);
    } else {
        pair_kernel_generic<<<F, BLOCK, 2 * S * sizeof(float), stream>>>(
            cent, v1, v2, v3, jd0, jd1, jd2, alpha, beta, face_probs, F, S, partial);
    }

    reduce_kernel<<<1, BLOCK, 0, stream>>>(partial, out, F, 1.0f / (float)F);
}